// Round 1
// baseline (1173.195 us; speedup 1.0000x reference)
//
#include <hip/hip_runtime.h>
#include <cstdint>
#include <cstddef>

#define EPSF 1e-8f

constexpr int NROWS = 32768;
constexpr int HALF  = 16384;
constexpr int KC    = 2048;
constexpr int DD    = 64;
constexpr int TK    = 256;   // codes per LDS tile
constexpr int NT    = 8;     // KC / TK
constexpr int WAVES = 8;     // per main block

// ---------- prep: z (b,d,h,w) -> z_flat (n,d), n = b*4096 + h*64 + w ----------
__global__ __launch_bounds__(256) void prep_z_kernel(const float* __restrict__ z,
                                                     float* __restrict__ zf) {
  __shared__ float t[64][65];
  const int bi  = blockIdx.x >> 6;          // batch
  const int hw0 = (blockIdx.x & 63) << 6;   // 64-chunk of h*64+w
  const int tid = threadIdx.x;
  for (int i = tid; i < 4096; i += 256) {
    int d = i >> 6, j = i & 63;
    t[d][j] = z[bi * 262144 + d * 4096 + hw0 + j];   // coalesced over j
  }
  __syncthreads();
  for (int i = tid; i < 4096; i += 256) {
    int j = i >> 6, d = i & 63;
    zf[(bi * 4096 + hw0 + j) * 64 + d] = t[d][j];    // coalesced over d
  }
}

// ---------- prep: embT[d][c] = emb[c][d]; embsq[c] = ||e_c||^2; zero accums ----------
__global__ __launch_bounds__(256) void prep_emb_kernel(const float* __restrict__ emb,
                                                       float* __restrict__ embT,
                                                       float* __restrict__ embsq,
                                                       double* __restrict__ accums) {
  __shared__ float t[64][65];
  const int c0  = blockIdx.x << 6;
  const int tid = threadIdx.x;
  if (blockIdx.x == 0 && tid < 4) accums[tid] = 0.0;
  for (int i = tid; i < 4096; i += 256) {
    int c = i >> 6, d = i & 63;
    t[c][d] = emb[(c0 + c) * 64 + d];                 // coalesced over d
  }
  __syncthreads();
  for (int i = tid; i < 4096; i += 256) {
    int d = i >> 6, c = i & 63;
    embT[d * KC + c0 + c] = t[c][d];                  // coalesced over c
  }
  if (tid < 64) {
    float s = 0.f;
    #pragma unroll
    for (int d = 0; d < 64; ++d) { float v = t[tid][d]; s = fmaf(v, v, s); }
    embsq[c0 + tid] = s;
  }
}

// ---------- main: per wave = one row pair (n, n+HALF) ----------
__global__ __launch_bounds__(512, 4) void main_kernel(
    const float* __restrict__ zf, const float* __restrict__ embT,
    const float* __restrict__ embsq, const float* __restrict__ emb,
    float* __restrict__ probs, int* __restrict__ minidx,
    double* __restrict__ accums)
{
  __shared__ float ebuf[DD][TK];     // 64 KB: embT tile [d][c]
  __shared__ float red[3][WAVES];

  const int tid  = threadIdx.x;
  const int w    = tid >> 6;
  const int lane = tid & 63;
  const int pair = blockIdx.x * WAVES + w;
  const int n0 = pair, n1 = pair + HALF;

  // lane d holds z[row][d]
  const float z0 = zf[n0 * DD + lane];
  const float z1 = zf[n1 * DD + lane];

  float acc0[NT][4], acc1[NT][4];
  #pragma unroll
  for (int t = 0; t < NT; ++t)
    #pragma unroll
    for (int j = 0; j < 4; ++j) { acc0[t][j] = 0.f; acc1[t][j] = 0.f; }

  #pragma unroll
  for (int t = 0; t < NT; ++t) {
    __syncthreads();
    // stage tile t: 64x256 floats, 512 threads x 8 float4 (coalesced, linear LDS)
    #pragma unroll
    for (int k = 0; k < 8; ++k) {
      int f = (tid << 2) + k * 2048;          // d = w + 8k, c = 4*lane
      int d = f >> 8, c = f & 255;
      float4 v = *(const float4*)(&embT[d * KC + t * TK + c]);
      *(float4*)(&ebuf[d][c]) = v;
    }
    __syncthreads();
    #pragma unroll
    for (int d = 0; d < DD; ++d) {
      float4 e = *(const float4*)(&ebuf[d][lane << 2]);
      float zd0 = __uint_as_float(__builtin_amdgcn_readlane(__float_as_uint(z0), d));
      float zd1 = __uint_as_float(__builtin_amdgcn_readlane(__float_as_uint(z1), d));
      acc0[t][0] = fmaf(zd0, e.x, acc0[t][0]);
      acc0[t][1] = fmaf(zd0, e.y, acc0[t][1]);
      acc0[t][2] = fmaf(zd0, e.z, acc0[t][2]);
      acc0[t][3] = fmaf(zd0, e.w, acc0[t][3]);
      acc1[t][0] = fmaf(zd1, e.x, acc1[t][0]);
      acc1[t][1] = fmaf(zd1, e.y, acc1[t][1]);
      acc1[t][2] = fmaf(zd1, e.z, acc1[t][2]);
      acc1[t][3] = fmaf(zd1, e.w, acc1[t][3]);
    }
  }

  // s = 2*dot - ||e||^2  (softmax(-dist) == softmax(s); argmin dist == argmax s)
  float bs0 = -1e30f, bs1 = -1e30f;
  int   bc0 = 0,      bc1 = 0;
  #pragma unroll
  for (int t = 0; t < NT; ++t) {
    float4 q = *(const float4*)(&embsq[t * TK + (lane << 2)]);
    #pragma unroll
    for (int j = 0; j < 4; ++j) {
      float qq = (j == 0 ? q.x : j == 1 ? q.y : j == 2 ? q.z : q.w);
      float s0 = fmaf(2.f, acc0[t][j], -qq);
      float s1 = fmaf(2.f, acc1[t][j], -qq);
      acc0[t][j] = s0; acc1[t][j] = s1;
      int col = t * TK + (lane << 2) + j;
      if (s0 > bs0) { bs0 = s0; bc0 = col; }
      if (s1 > bs1) { bs1 = s1; bc1 = col; }
    }
  }
  // cross-lane argmax (tie -> lower col, matching argmin-first semantics)
  #pragma unroll
  for (int m = 32; m; m >>= 1) {
    float os0 = __shfl_xor(bs0, m); int oc0 = __shfl_xor(bc0, m);
    if (os0 > bs0 || (os0 == bs0 && oc0 < bc0)) { bs0 = os0; bc0 = oc0; }
    float os1 = __shfl_xor(bs1, m); int oc1 = __shfl_xor(bc1, m);
    if (os1 > bs1 || (os1 == bs1 && oc1 < bc1)) { bs1 = os1; bc1 = oc1; }
  }
  const float fm0 = bs0, fm1 = bs1;   // row maxima

  // softmax
  float sum0 = 0.f, sum1 = 0.f;
  #pragma unroll
  for (int t = 0; t < NT; ++t)
    #pragma unroll
    for (int j = 0; j < 4; ++j) {
      float e0 = __expf(acc0[t][j] - fm0);
      float e1 = __expf(acc1[t][j] - fm1);
      acc0[t][j] = e0; acc1[t][j] = e1;
      sum0 += e0; sum1 += e1;
    }
  #pragma unroll
  for (int m = 32; m; m >>= 1) { sum0 += __shfl_xor(sum0, m); sum1 += __shfl_xor(sum1, m); }
  const float inv0 = 1.f / sum0, inv1 = 1.f / sum1;

  // write probs + JSD/entropy partials (both rows of the pair are in-register)
  float kl = 0.f, ent = 0.f;
  float* p0out = probs + (size_t)n0 * KC;
  float* p1out = probs + (size_t)n1 * KC;
  #pragma unroll
  for (int t = 0; t < NT; ++t)
    #pragma unroll
    for (int j = 0; j < 4; ++j) {
      int col = t * TK + (lane << 2) + j;
      float p1 = acc0[t][j] * inv0;
      float p2 = acc1[t][j] * inv1;
      p0out[col] = p1;
      p1out[col] = p2;
      float mm = 0.5f * (p1 + p2);
      float l1 = __logf(p1 + EPSF);
      float l2 = __logf(p2 + EPSF);
      float lm = __logf(mm + EPSF);
      float t1 = p1 * l1, t2 = p2 * l2;
      kl  += (t1 + t2) - (p1 + p2) * lm;   // kl1[n] + kl2[n] contribution
      ent -= (t1 + t2);                    // ent1[n] + ent2[n] contribution
    }

  // q_loss partial: (emb[argmin] - z)^2 for both rows
  float d0 = emb[bc0 * DD + lane] - z0;
  float d1 = emb[bc1 * DD + lane] - z1;
  float sq = d0 * d0 + d1 * d1;

  #pragma unroll
  for (int m = 32; m; m >>= 1) {
    kl  += __shfl_xor(kl, m);
    ent += __shfl_xor(ent, m);
    sq  += __shfl_xor(sq, m);
  }
  if (lane == 0) {
    minidx[n0] = bc0; minidx[n1] = bc1;
    red[0][w] = kl; red[1][w] = ent; red[2][w] = sq;
  }
  __syncthreads();
  if (tid == 0) {
    double a = 0.0, b = 0.0, c = 0.0;
    #pragma unroll
    for (int i = 0; i < WAVES; ++i) { a += (double)red[0][i]; b += (double)red[1][i]; c += (double)red[2][i]; }
    atomicAdd(&accums[0], a);   // sum over pairs of (kl1+kl2)
    atomicAdd(&accums[1], b);   // sum over pairs of (ent1+ent2)
    atomicAdd(&accums[2], c);   // sum of squared diffs
  }
}

// ---------- epilogue: z_q_out transpose-gather + scalar finalize ----------
__global__ __launch_bounds__(256) void zqout_kernel(const float* __restrict__ emb,
                                                    const int* __restrict__ minidx,
                                                    const double* __restrict__ accums,
                                                    float* __restrict__ out) {
  const int o  = blockIdx.x * 256 + threadIdx.x;     // flat (b,d,h,w)
  const int w_ = o & 63;
  const int h  = (o >> 6) & 63;
  const int d  = (o >> 12) & 63;
  const int b  = o >> 18;
  const int n  = b * 4096 + h * 64 + w_;
  out[o] = emb[minidx[n] * 64 + d];
  if (o == 0) {
    out[2097152] = (float)(1.25 * accums[2] / 2097152.0);   // q_loss
    out[2097153] = (float)(0.5 * accums[0] / 16384.0);      // jsd
    out[2097154] = (float)(accums[1] / 32768.0);            // entropy
  }
}

extern "C" void kernel_launch(void* const* d_in, const int* in_sizes, int n_in,
                              void* d_out, int out_size, void* d_ws, size_t ws_size,
                              hipStream_t stream) {
  const float* z   = (const float*)d_in[0];
  const float* emb = (const float*)d_in[1];
  float* out = (float*)d_out;

  // workspace layout
  float*  zf     = (float*)d_ws;            // 2097152 floats
  float*  embT   = zf + 2097152;            // 131072
  float*  embsq  = embT + 131072;           // 2048
  int*    minidx = (int*)(embsq + 2048);    // 32768 ints
  double* accums = (double*)(minidx + 32768); // 4 doubles (8B aligned)

  float* probs = out + 2097155;             // after z_q_out + 3 scalars

  prep_z_kernel  <<<512,  256, 0, stream>>>(z, zf);
  prep_emb_kernel<<<32,   256, 0, stream>>>(emb, embT, embsq, accums);
  main_kernel    <<<2048, 512, 0, stream>>>(zf, embT, embsq, emb, probs, minidx, accums);
  zqout_kernel   <<<8192, 256, 0, stream>>>(emb, minidx, accums, out);
}

// Round 2
// 353.059 us; speedup vs baseline: 3.3229x; 3.3229x over previous
//
#include <hip/hip_runtime.h>
#include <cstdint>
#include <cstddef>

#define EPSF 1e-8f

constexpr int HALF = 16384;
constexpr int KC   = 2048;
constexpr int DD   = 64;
constexpr int TK   = 128;   // codes per LDS tile
constexpr int NT   = 16;    // KC / TK

// ---------- prep: z (b,d,h,w) -> z_flat (n,d), n = b*4096 + h*64 + w ----------
__global__ __launch_bounds__(256) void prep_z_kernel(const float* __restrict__ z,
                                                     float* __restrict__ zf) {
  __shared__ float t[64][65];
  const int bi  = blockIdx.x >> 6;
  const int hw0 = (blockIdx.x & 63) << 6;
  const int tid = threadIdx.x;
  for (int i = tid; i < 4096; i += 256) {
    int d = i >> 6, j = i & 63;
    t[d][j] = z[bi * 262144 + d * 4096 + hw0 + j];
  }
  __syncthreads();
  for (int i = tid; i < 4096; i += 256) {
    int j = i >> 6, d = i & 63;
    zf[(bi * 4096 + hw0 + j) * 64 + d] = t[d][j];
  }
}

// ---------- prep: emb -> swizzled embT + embsq; zero accums ----------
// Swizzle: for global col C, tile tt=C>>7, u=C&127: LDS-linear pos = 2*(u&63) + (u>>6).
// Then main kernel's ds_read_b64 at float2 index [d*64+lane] yields cols {l, 64+l}.
__global__ __launch_bounds__(256) void prep_emb_kernel(const float* __restrict__ emb,
                                                       float* __restrict__ embT,
                                                       float* __restrict__ embsq,
                                                       double* __restrict__ accums) {
  __shared__ float t[64][65];
  const int c0  = blockIdx.x << 6;
  const int tid = threadIdx.x;
  if (blockIdx.x == 0 && tid < 4) accums[tid] = 0.0;
  for (int i = tid; i < 4096; i += 256) {
    int c = i >> 6, d = i & 63;
    t[c][d] = emb[(c0 + c) * 64 + d];
  }
  __syncthreads();
  for (int i = tid; i < 4096; i += 256) {
    int d = i >> 6, c = i & 63;
    int C = c0 + c;
    int u = C & (TK - 1);
    int pos = ((u & 63) << 1) + (u >> 6);
    embT[d * KC + (C >> 7) * TK + pos] = t[c][d];
  }
  if (tid < 64) {
    float s = 0.f;
    #pragma unroll
    for (int d = 0; d < 64; ++d) { float v = t[tid][d]; s = fmaf(v, v, s); }
    embsq[c0 + tid] = s;
  }
}

__device__ __forceinline__ float bcast(float v, int d) {
  return __uint_as_float(__builtin_amdgcn_readlane(__float_as_uint(v), d));
}

// ---------- main: per wave = 2 row pairs (pb,pb+1) x (.., ..+HALF) ----------
__global__ __launch_bounds__(256, 3) void main_kernel(
    const float* __restrict__ zf, const float* __restrict__ embT,
    const float* __restrict__ embsq, const float* __restrict__ emb,
    float* __restrict__ probs, int* __restrict__ minidx,
    double* __restrict__ accums)
{
  __shared__ float ebuf[DD * TK];   // 32 KB, linear (matches pre-swizzled embT)
  __shared__ float red[3][4];

  const int tid  = threadIdx.x;
  const int w    = tid >> 6;
  const int lane = tid & 63;
  const int pb   = (blockIdx.x * 4 + w) * 2;
  const int n0 = pb, n1 = pb + 1, n2 = pb + HALF, n3 = pb + 1 + HALF;

  const float z0 = zf[n0 * DD + lane];
  const float z1 = zf[n1 * DD + lane];
  const float z2 = zf[n2 * DD + lane];
  const float z3 = zf[n3 * DD + lane];

  float a0[NT][2], a1[NT][2], a2[NT][2], a3[NT][2];
  #pragma unroll
  for (int t = 0; t < NT; ++t) {
    a0[t][0] = a0[t][1] = 0.f; a1[t][0] = a1[t][1] = 0.f;
    a2[t][0] = a2[t][1] = 0.f; a3[t][0] = a3[t][1] = 0.f;
  }

  #pragma unroll
  for (int t = 0; t < NT; ++t) {
    __syncthreads();
    // stage tile t: 32 segments of 1KB via global_load_lds (linear LDS dest)
    #pragma unroll
    for (int k = 0; k < 8; ++k) {
      int g = w * 8 + k;
      const float* src = embT + (2 * g + (lane >> 5)) * KC + t * TK + ((lane & 31) << 2);
      __builtin_amdgcn_global_load_lds(
          (const __attribute__((address_space(1))) void*)src,
          (__attribute__((address_space(3))) void*)(ebuf + g * 256), 16, 0, 0);
    }
    __syncthreads();
    const float2* eb = (const float2*)ebuf;
    #pragma unroll 4
    for (int d = 0; d < DD; ++d) {
      float2 e = eb[d * 64 + lane];     // cols {lane, 64+lane} of tile t
      float zd0 = bcast(z0, d), zd1 = bcast(z1, d), zd2 = bcast(z2, d), zd3 = bcast(z3, d);
      a0[t][0] = fmaf(zd0, e.x, a0[t][0]); a0[t][1] = fmaf(zd0, e.y, a0[t][1]);
      a1[t][0] = fmaf(zd1, e.x, a1[t][0]); a1[t][1] = fmaf(zd1, e.y, a1[t][1]);
      a2[t][0] = fmaf(zd2, e.x, a2[t][0]); a2[t][1] = fmaf(zd2, e.y, a2[t][1]);
      a3[t][0] = fmaf(zd3, e.x, a3[t][0]); a3[t][1] = fmaf(zd3, e.y, a3[t][1]);
    }
  }

  // s = 2*dot - ||e||^2 ; argmax == argmin dist
  float bs0 = -1e30f, bs1 = -1e30f, bs2 = -1e30f, bs3 = -1e30f;
  int   bc0 = 0, bc1 = 0, bc2 = 0, bc3 = 0;
  #pragma unroll
  for (int t = 0; t < NT; ++t)
    #pragma unroll
    for (int s = 0; s < 2; ++s) {
      float qq = embsq[t * TK + s * 64 + lane];
      int col = t * TK + s * 64 + lane;
      float v;
      v = fmaf(2.f, a0[t][s], -qq); a0[t][s] = v; if (v > bs0) { bs0 = v; bc0 = col; }
      v = fmaf(2.f, a1[t][s], -qq); a1[t][s] = v; if (v > bs1) { bs1 = v; bc1 = col; }
      v = fmaf(2.f, a2[t][s], -qq); a2[t][s] = v; if (v > bs2) { bs2 = v; bc2 = col; }
      v = fmaf(2.f, a3[t][s], -qq); a3[t][s] = v; if (v > bs3) { bs3 = v; bc3 = col; }
    }
  #pragma unroll
  for (int m = 32; m; m >>= 1) {
    float os; int oc;
    os = __shfl_xor(bs0, m); oc = __shfl_xor(bc0, m);
    if (os > bs0 || (os == bs0 && oc < bc0)) { bs0 = os; bc0 = oc; }
    os = __shfl_xor(bs1, m); oc = __shfl_xor(bc1, m);
    if (os > bs1 || (os == bs1 && oc < bc1)) { bs1 = os; bc1 = oc; }
    os = __shfl_xor(bs2, m); oc = __shfl_xor(bc2, m);
    if (os > bs2 || (os == bs2 && oc < bc2)) { bs2 = os; bc2 = oc; }
    os = __shfl_xor(bs3, m); oc = __shfl_xor(bc3, m);
    if (os > bs3 || (os == bs3 && oc < bc3)) { bs3 = os; bc3 = oc; }
  }

  // softmax (numerically safe with row-max subtract)
  float s0 = 0.f, s1 = 0.f, s2 = 0.f, s3 = 0.f;
  #pragma unroll
  for (int t = 0; t < NT; ++t)
    #pragma unroll
    for (int s = 0; s < 2; ++s) {
      float e;
      e = __expf(a0[t][s] - bs0); a0[t][s] = e; s0 += e;
      e = __expf(a1[t][s] - bs1); a1[t][s] = e; s1 += e;
      e = __expf(a2[t][s] - bs2); a2[t][s] = e; s2 += e;
      e = __expf(a3[t][s] - bs3); a3[t][s] = e; s3 += e;
    }
  #pragma unroll
  for (int m = 32; m; m >>= 1) {
    s0 += __shfl_xor(s0, m); s1 += __shfl_xor(s1, m);
    s2 += __shfl_xor(s2, m); s3 += __shfl_xor(s3, m);
  }
  const float inv0 = 1.f / s0, inv1 = 1.f / s1, inv2 = 1.f / s2, inv3 = 1.f / s3;

  // write probs (dense 256B/instr) + JSD/entropy partials
  float kl = 0.f, ent = 0.f;
  {
    float* pA = probs + (size_t)n0 * KC;
    float* pB = probs + (size_t)n2 * KC;
    #pragma unroll
    for (int t = 0; t < NT; ++t)
      #pragma unroll
      for (int s = 0; s < 2; ++s) {
        int col = t * TK + s * 64 + lane;
        float p1 = a0[t][s] * inv0;
        float p2 = a2[t][s] * inv2;
        pA[col] = p1; pB[col] = p2;
        float mm = 0.5f * (p1 + p2);
        float l1 = __logf(p1 + EPSF), l2 = __logf(p2 + EPSF), lm = __logf(mm + EPSF);
        float t1 = p1 * l1, t2 = p2 * l2;
        kl  += (t1 + t2) - (p1 + p2) * lm;
        ent -= (t1 + t2);
      }
  }
  {
    float* pA = probs + (size_t)n1 * KC;
    float* pB = probs + (size_t)n3 * KC;
    #pragma unroll
    for (int t = 0; t < NT; ++t)
      #pragma unroll
      for (int s = 0; s < 2; ++s) {
        int col = t * TK + s * 64 + lane;
        float p1 = a1[t][s] * inv1;
        float p2 = a3[t][s] * inv3;
        pA[col] = p1; pB[col] = p2;
        float mm = 0.5f * (p1 + p2);
        float l1 = __logf(p1 + EPSF), l2 = __logf(p2 + EPSF), lm = __logf(mm + EPSF);
        float t1 = p1 * l1, t2 = p2 * l2;
        kl  += (t1 + t2) - (p1 + p2) * lm;
        ent -= (t1 + t2);
      }
  }

  // q_loss partials
  float d0 = emb[bc0 * DD + lane] - z0;
  float d1 = emb[bc1 * DD + lane] - z1;
  float d2 = emb[bc2 * DD + lane] - z2;
  float d3 = emb[bc3 * DD + lane] - z3;
  float sq = d0 * d0 + d1 * d1 + d2 * d2 + d3 * d3;

  #pragma unroll
  for (int m = 32; m; m >>= 1) {
    kl  += __shfl_xor(kl, m);
    ent += __shfl_xor(ent, m);
    sq  += __shfl_xor(sq, m);
  }
  if (lane == 0) {
    minidx[n0] = bc0; minidx[n1] = bc1; minidx[n2] = bc2; minidx[n3] = bc3;
    red[0][w] = kl; red[1][w] = ent; red[2][w] = sq;
  }
  __syncthreads();
  if (tid == 0) {
    double a = 0.0, b = 0.0, c = 0.0;
    #pragma unroll
    for (int i = 0; i < 4; ++i) { a += (double)red[0][i]; b += (double)red[1][i]; c += (double)red[2][i]; }
    atomicAdd(&accums[0], a);
    atomicAdd(&accums[1], b);
    atomicAdd(&accums[2], c);
  }
}

// ---------- epilogue: z_q_out transpose-gather + scalar finalize ----------
__global__ __launch_bounds__(256) void zqout_kernel(const float* __restrict__ emb,
                                                    const int* __restrict__ minidx,
                                                    const double* __restrict__ accums,
                                                    float* __restrict__ out) {
  const int o  = blockIdx.x * 256 + threadIdx.x;
  const int w_ = o & 63;
  const int h  = (o >> 6) & 63;
  const int d  = (o >> 12) & 63;
  const int b  = o >> 18;
  const int n  = b * 4096 + h * 64 + w_;
  out[o] = emb[minidx[n] * 64 + d];
  if (o == 0) {
    out[2097152] = (float)(1.25 * accums[2] / 2097152.0);   // q_loss
    out[2097153] = (float)(0.5 * accums[0] / 16384.0);      // jsd
    out[2097154] = (float)(accums[1] / 32768.0);            // entropy
  }
}

extern "C" void kernel_launch(void* const* d_in, const int* in_sizes, int n_in,
                              void* d_out, int out_size, void* d_ws, size_t ws_size,
                              hipStream_t stream) {
  const float* z   = (const float*)d_in[0];
  const float* emb = (const float*)d_in[1];
  float* out = (float*)d_out;

  float*  zf     = (float*)d_ws;              // 2097152 floats
  float*  embT   = zf + 2097152;              // 131072 (swizzled)
  float*  embsq  = embT + 131072;             // 2048
  int*    minidx = (int*)(embsq + 2048);      // 32768 ints
  double* accums = (double*)(minidx + 32768); // 4 doubles

  float* probs = out + 2097155;

  prep_z_kernel  <<<512,  256, 0, stream>>>(z, zf);
  prep_emb_kernel<<<32,   256, 0, stream>>>(emb, embT, embsq, accums);
  main_kernel    <<<2048, 256, 0, stream>>>(zf, embT, embsq, emb, probs, minidx, accums);
  zqout_kernel   <<<8192, 256, 0, stream>>>(emb, minidx, accums, out);
}

// Round 3
// 233.281 us; speedup vs baseline: 5.0291x; 1.5135x over previous
//
#include <hip/hip_runtime.h>
#include <cstdint>
#include <cstddef>

#define EPSF 1e-8f
constexpr int HALF = 16384;
constexpr int KC   = 2048;

typedef __attribute__((ext_vector_type(8)))  short short8v;
typedef __attribute__((ext_vector_type(16))) float f32x16;

__device__ __forceinline__ unsigned short f2bf_rn(float f) {
  unsigned u = __float_as_uint(f);
  unsigned r = (u + 0x7fffu + ((u >> 16) & 1u)) >> 16;
  return (unsigned short)r;
}
__device__ __forceinline__ float bf2f(unsigned short b) {
  return __uint_as_float(((unsigned)b) << 16);
}
__device__ __forceinline__ float wave_red_sum(float v) {
  #pragma unroll
  for (int m = 32; m; m >>= 1) v += __shfl_xor(v, m);
  return v;
}

// ---------- prep: z (b,d,h,w) -> z_flat (n,d) fp32 ----------
__global__ __launch_bounds__(256) void prep_z_kernel(const float* __restrict__ z,
                                                     float* __restrict__ zf) {
  __shared__ float t[64][65];
  const int bi  = blockIdx.x >> 6;
  const int hw0 = (blockIdx.x & 63) << 6;
  const int tid = threadIdx.x;
  for (int i = tid; i < 4096; i += 256) {
    int d = i >> 6, j = i & 63;
    t[d][j] = z[bi * 262144 + d * 4096 + hw0 + j];
  }
  __syncthreads();
  for (int i = tid; i < 4096; i += 256) {
    int j = i >> 6, d = i & 63;
    zf[(bi * 4096 + hw0 + j) * 64 + d] = t[d][j];
  }
}

// ---------- prep: emb -> bf16 hi/lo + ||e||^2 ; zero accums ----------
__global__ __launch_bounds__(256) void prep_emb_kernel(const float* __restrict__ emb,
    unsigned short* __restrict__ ebh, unsigned short* __restrict__ ebl,
    float* __restrict__ embsq, double* __restrict__ accums) {
  const int c = blockIdx.x * 256 + threadIdx.x;
  if (blockIdx.x == 0 && threadIdx.x < 4) accums[threadIdx.x] = 0.0;
  float s = 0.f;
  for (int d = 0; d < 64; ++d) {
    float v = emb[c * 64 + d];
    unsigned short hb = f2bf_rn(v);
    ebh[c * 64 + d] = hb;
    ebl[c * 64 + d] = f2bf_rn(v - bf2f(hb));
    s = fmaf(v, v, s);
  }
  embsq[c] = s;
}

// ---------- main: 1024 blocks x 512 thr; 32 rows (16 JSD pairs) x 2048 cols ----------
__global__ __launch_bounds__(512) void main_kernel(
    const float* __restrict__ zf,
    const unsigned short* __restrict__ ebh, const unsigned short* __restrict__ ebl,
    const float* __restrict__ embsq, const float* __restrict__ emb,
    float* __restrict__ probs, int* __restrict__ minidx, double* __restrict__ accums)
{
  __shared__ float2 red2[32][260];   // 65 KB reduction scratch (2-way free on dump)
  __shared__ float  g_inv[32], g_plp[32];
  __shared__ int    g_idx[32];
  __shared__ float  red_sc[2][8];
  __shared__ float  plp_s;

  const int tid = threadIdx.x;
  const int w   = tid >> 6, lane = tid & 63;
  const int l31 = lane & 31, h = lane >> 5;
  const int n0  = blockIdx.x * 16;
  const int wc0 = w * 256;

  // ---- A fragments: row = l31 (rows 0-15 low half, 16-31 high half), split fp32->bf16 hi/lo
  const int an = (l31 < 16) ? (n0 + l31) : (HALF + n0 + l31 - 16);
  const float* zrow = zf + an * 64;
  short8v Ah[4], Al[4];
  #pragma unroll
  for (int c = 0; c < 4; ++c) {
    #pragma unroll
    for (int j = 0; j < 8; ++j) {
      float v = zrow[c * 16 + h * 8 + j];
      unsigned short hb = f2bf_rn(v);
      unsigned short lb = f2bf_rn(v - bf2f(hb));
      Ah[c][j] = (short)hb;
      Al[c][j] = (short)lb;
    }
  }

  f32x16 acc[8];
  #pragma unroll
  for (int t = 0; t < 8; ++t)
    #pragma unroll
    for (int k = 0; k < 16; ++k) acc[t][k] = 0.f;

  // ---- MFMA: dot[row][col], 8 col-tiles x 4 K-chunks x 3 split terms
  #pragma unroll
  for (int t = 0; t < 8; ++t) {
    const int col = wc0 + t * 32 + l31;
    const unsigned short* bh = ebh + col * 64 + h * 8;
    const unsigned short* bl = ebl + col * 64 + h * 8;
    #pragma unroll
    for (int c = 0; c < 4; ++c) {
      short8v Bh = *(const short8v*)(bh + c * 16);
      short8v Bl = *(const short8v*)(bl + c * 16);
      acc[t] = __builtin_amdgcn_mfma_f32_32x32x16_bf16(Ah[c], Bh, acc[t], 0, 0, 0);
      acc[t] = __builtin_amdgcn_mfma_f32_32x32x16_bf16(Al[c], Bh, acc[t], 0, 0, 0);
      acc[t] = __builtin_amdgcn_mfma_f32_32x32x16_bf16(Ah[c], Bl, acc[t], 0, 0, 0);
    }
  }

  // ---- phase 1: s = 2*dot - ||e||^2; e = exp(s); per-(lane,row) partials
  float mx[16], es[16], eu[16];
  int   mc[16];
  #pragma unroll
  for (int k = 0; k < 16; ++k) { mx[k] = -1e30f; es[k] = 0.f; eu[k] = 0.f; mc[k] = 0; }
  #pragma unroll
  for (int t = 0; t < 8; ++t) {
    const int col = wc0 + t * 32 + l31;
    const float q = embsq[col];
    #pragma unroll
    for (int k = 0; k < 16; ++k) {
      float s = fmaf(2.f, acc[t][k], -q);
      float e = __expf(s);
      if (s > mx[k]) { mx[k] = s; mc[k] = col; }   // ascending col -> first max kept
      es[k] += e;
      eu[k] = fmaf(e, s, eu[k]);
      acc[t][k] = e;
    }
  }

  const int slot = w * 32 + l31;
  // ---- phase 2a: row sums (esum, e*s) across 256 lane-slots
  #pragma unroll
  for (int k = 0; k < 16; ++k) {
    int row = (k & 3) + 8 * (k >> 2) + 4 * h;
    red2[row][slot] = make_float2(es[k], eu[k]);
  }
  __syncthreads();
  if (tid < 256) {
    int row = tid >> 3, j = tid & 7;
    float S = 0.f, U = 0.f;
    #pragma unroll 8
    for (int i = 0; i < 32; ++i) {
      float2 v = red2[row][j * 32 + i];
      S += v.x; U += v.y;
    }
    #pragma unroll
    for (int m = 1; m < 8; m <<= 1) { S += __shfl_xor(S, m); U += __shfl_xor(U, m); }
    if (j == 0) {
      g_inv[row] = 1.f / S;
      // sum_k p*log(p+eps) = U/S - ln(S) + K*eps   (exp taken without max-shift)
      g_plp[row] = U / S - logf(S) + (float)KC * EPSF;
    }
  }
  __syncthreads();
  // ---- phase 2b: row argmax (=argmin dist), tie -> lowest col
  #pragma unroll
  for (int k = 0; k < 16; ++k) {
    int row = (k & 3) + 8 * (k >> 2) + 4 * h;
    red2[row][slot] = make_float2(mx[k], __int_as_float(mc[k]));
  }
  __syncthreads();
  if (tid < 256) {
    int row = tid >> 3, j = tid & 7;
    float M = -1e30f; int C = 0x7fffffff;
    #pragma unroll 8
    for (int i = 0; i < 32; ++i) {
      float2 v = red2[row][j * 32 + i];
      int c = __float_as_int(v.y);
      if (v.x > M || (v.x == M && c < C)) { M = v.x; C = c; }
    }
    #pragma unroll
    for (int m = 1; m < 8; m <<= 1) {
      float oM = __shfl_xor(M, m); int oC = __shfl_xor(C, m);
      if (oM > M || (oM == M && oC < C)) { M = oM; C = oC; }
    }
    if (j == 0) {
      g_idx[row] = C;
      int n = (row < 16) ? (n0 + row) : (HALF + n0 + row - 16);
      minidx[n] = C;
    }
  }
  __syncthreads();

  // ---- phase 3: normalize, store probs (2x128B dense lines/instr), mixture-log partial
  float vinv[16];
  #pragma unroll
  for (int k = 0; k < 16; ++k) vinv[k] = g_inv[(k & 3) + 8 * (k >> 2) + 4 * h];
  float klm = 0.f;
  #pragma unroll
  for (int t = 0; t < 8; ++t) {
    const int col = wc0 + t * 32 + l31;
    #pragma unroll
    for (int k = 0; k < 8; ++k) {
      int r   = (k & 3) + 8 * (k >> 2) + 4 * h;   // low row; pair row = r+16 (reg k+8)
      int nlo = n0 + r;
      float p1 = acc[t][k]     * vinv[k];
      float p2 = acc[t][k + 8] * vinv[k + 8];
      probs[(size_t)nlo * KC + col] = p1;
      probs[(size_t)(nlo + HALF) * KC + col] = p2;
      float ps = p1 + p2;
      klm = fmaf(ps, __logf(fmaf(0.5f, ps, EPSF)), klm);
    }
  }
  klm = wave_red_sum(klm);

  // ---- q_loss partial: (emb[argmin] - z)^2, block-wide coalesced
  float sq = 0.f;
  #pragma unroll
  for (int p = 0; p < 4; ++p) {
    int idx = tid + p * 512;
    int row = idx >> 6, d = idx & 63;
    int n = (row < 16) ? (n0 + row) : (HALF + n0 + row - 16);
    float diff = emb[g_idx[row] * 64 + d] - zf[n * 64 + d];
    sq = fmaf(diff, diff, sq);
  }
  sq = wave_red_sum(sq);
  if (lane == 0) { red_sc[0][w] = klm; red_sc[1][w] = sq; }
  if (tid < 32) {
    float plp = g_plp[tid];
    #pragma unroll
    for (int m = 1; m < 32; m <<= 1) plp += __shfl_xor(plp, m);
    if (tid == 0) plp_s = plp;
  }
  __syncthreads();
  if (tid == 0) {
    float K = 0.f, Q = 0.f;
    #pragma unroll
    for (int i = 0; i < 8; ++i) { K += red_sc[0][i]; Q += red_sc[1][i]; }
    atomicAdd(&accums[0], (double)(plp_s - K));   // sum over pairs (kl1+kl2)
    atomicAdd(&accums[1], (double)(-plp_s));      // sum over pairs (ent1+ent2)
    atomicAdd(&accums[2], (double)Q);             // sum sq diffs
  }
}

// ---------- epilogue: z_q_out transpose-gather + scalar finalize ----------
__global__ __launch_bounds__(256) void zqout_kernel(const float* __restrict__ emb,
                                                    const int* __restrict__ minidx,
                                                    const double* __restrict__ accums,
                                                    float* __restrict__ out) {
  const int o  = blockIdx.x * 256 + threadIdx.x;
  const int w_ = o & 63;
  const int hh = (o >> 6) & 63;
  const int d  = (o >> 12) & 63;
  const int b  = o >> 18;
  const int n  = b * 4096 + hh * 64 + w_;
  out[o] = emb[minidx[n] * 64 + d];
  if (o == 0) {
    out[2097152] = (float)(1.25 * accums[2] / 2097152.0);   // q_loss
    out[2097153] = (float)(0.5 * accums[0] / 16384.0);      // jsd
    out[2097154] = (float)(accums[1] / 32768.0);            // entropy
  }
}

extern "C" void kernel_launch(void* const* d_in, const int* in_sizes, int n_in,
                              void* d_out, int out_size, void* d_ws, size_t ws_size,
                              hipStream_t stream) {
  const float* z   = (const float*)d_in[0];
  const float* emb = (const float*)d_in[1];
  float* out = (float*)d_out;

  float*          zf     = (float*)d_ws;                   // 8 MB
  unsigned short* ebh    = (unsigned short*)(zf + 2097152); // 256 KB
  unsigned short* ebl    = ebh + 131072;                    // 256 KB
  float*          embsq  = (float*)(ebl + 131072);          // 8 KB
  int*            minidx = (int*)(embsq + 2048);            // 128 KB
  double*         accums = (double*)(minidx + 32768);       // 32 B

  float* probs = out + 2097155;

  prep_z_kernel  <<<512,  256, 0, stream>>>(z, zf);
  prep_emb_kernel<<<8,    256, 0, stream>>>(emb, ebh, ebl, embsq, accums);
  main_kernel    <<<1024, 512, 0, stream>>>(zf, ebh, ebl, embsq, emb, probs, minidx, accums);
  zqout_kernel   <<<8192, 256, 0, stream>>>(emb, minidx, accums, out);
}